// Round 1
// baseline (658.228 us; speedup 1.0000x reference)
//
#include <hip/hip_runtime.h>
#include <math.h>

#define B_  128
#define C_  512
#define S_  128
#define M_  512
#define BN_EPS 1e-5f

typedef __attribute__((ext_vector_type(8))) short   short8;
typedef __attribute__((ext_vector_type(4))) float   floatx4;
typedef __attribute__((ext_vector_type(4))) unsigned short ushort4v;

// fp32 -> bf16 bits, round-to-nearest-even (finite inputs)
__device__ __forceinline__ unsigned short f2bu(float f) {
    union { float f; unsigned int u; } c; c.f = f;
    unsigned int u = c.u;
    return (unsigned short)((u + 0x7fffu + ((u >> 16) & 1u)) >> 16);
}

// ---------------------------------------------------------------------------
// fp32 -> bf16, 8 elems/thread. 3-input variant (query/key/value), outputs
// contiguous at out + z*8*n8.
// ---------------------------------------------------------------------------
__global__ __launch_bounds__(256)
void f2bf3_kernel(const float* __restrict__ a0, const float* __restrict__ a1,
                  const float* __restrict__ a2, unsigned short* __restrict__ out,
                  long n8)
{
    const float* in = (blockIdx.y == 0) ? a0 : (blockIdx.y == 1) ? a1 : a2;
    unsigned short* o = out + (long)blockIdx.y * (n8 * 8);
    const long i = (long)blockIdx.x * 256 + threadIdx.x;
    if (i >= n8) return;
    const float4* p = (const float4*)in + 2 * i;
    const float4 x = p[0], y = p[1];
    ushort4v u0, u1;
    u0.x = f2bu(x.x); u0.y = f2bu(x.y); u0.z = f2bu(x.z); u0.w = f2bu(x.w);
    u1.x = f2bu(y.x); u1.y = f2bu(y.y); u1.z = f2bu(y.z); u1.w = f2bu(y.w);
    ((ushort4v*)o)[2 * i]     = u0;
    ((ushort4v*)o)[2 * i + 1] = u1;
}

// 4-input variant for the weight matrices (all M_*S_ elems each).
__global__ __launch_bounds__(256)
void f2bf4_kernel(const float* __restrict__ a0, const float* __restrict__ a1,
                  const float* __restrict__ a2, const float* __restrict__ a3,
                  unsigned short* __restrict__ out, long n8)
{
    const float* in = (blockIdx.y == 0) ? a0 : (blockIdx.y == 1) ? a1
                    : (blockIdx.y == 2) ? a2 : a3;
    unsigned short* o = out + (long)blockIdx.y * (n8 * 8);
    const long i = (long)blockIdx.x * 256 + threadIdx.x;
    if (i >= n8) return;
    const float4* p = (const float4*)in + 2 * i;
    const float4 x = p[0], y = p[1];
    ushort4v u0, u1;
    u0.x = f2bu(x.x); u0.y = f2bu(x.y); u0.z = f2bu(x.z); u0.w = f2bu(x.w);
    u1.x = f2bu(y.x); u1.y = f2bu(y.y); u1.z = f2bu(y.z); u1.w = f2bu(y.w);
    ((ushort4v*)o)[2 * i]     = u0;
    ((ushort4v*)o)[2 * i + 1] = u1;
}

// ---------------------------------------------------------------------------
// Pack bq/bk/bv contiguous ([3][512]) and zero the BN stats accumulators.
// ---------------------------------------------------------------------------
__global__ __launch_bounds__(256)
void pack_bias_zero_stats(const float* __restrict__ bq, const float* __restrict__ bk,
                          const float* __restrict__ bv, float* __restrict__ bqkv,
                          float* __restrict__ stats)
{
    const int t = blockIdx.x * 256 + threadIdx.x;
    if (t < 512)            bqkv[t] = bq[t];
    else if (t < 1024)      bqkv[t] = bk[t - 512];
    else if (t < 1536)      bqkv[t] = bv[t - 1024];
    else if (t < 1536 + 2 * C_) stats[t - 1536] = 0.f;
}

// ---------------------------------------------------------------------------
// bf16 MFMA GEMM, NT form: C[i,j] = scale * sum_k A[i,k]*Bm[j,k] (+ bias[j])
//   Batched over blockIdx.z with element strides sA/sB/sC/sBias.
//   outMode 0: fp32 C [ldC];  1: bf16 C [ldC];
//           2: bf16 scattered vwT: addr = (r>>9)*65536 + col*512 + (r&511)
//   STATS: accumulate per-row sum/sumsq of fp32 output into statsOut via
//   atomics (used by the context GEMM; rows == BN channels).
// Tile: BM=BN=128, BK=64. 256 thr = 4 waves (2x2), each wave 64x64 via
// 4x4 grid of 16x16x32 MFMA. LDS rows padded to 72 bf16.
// ---------------------------------------------------------------------------
template<bool STATS>
__global__ __launch_bounds__(256)
void gemm_bf16(const unsigned short* __restrict__ A, const unsigned short* __restrict__ Bm,
               const float* __restrict__ bias, void* __restrict__ Cc,
               int M, int N, int K, int ldA, int ldB, int ldC,
               long sA, long sB, long sC, long sBias, float scale, int outMode,
               float* __restrict__ statsOut)
{
    const int bz = blockIdx.z;
    A  += (long)bz * sA;
    Bm += (long)bz * sB;
    if (bias) bias += (long)bz * sBias;

    __shared__ unsigned short As[128][72];
    __shared__ unsigned short Bs[128][72];

    const int t    = threadIdx.x;
    const int lane = t & 63;
    const int wave = t >> 6;          // 0..3
    const int wm   = (wave >> 1) * 64;
    const int wn   = (wave & 1) * 64;
    const int lrow = lane & 15;
    const int quad = lane >> 4;
    const int row0 = blockIdx.x * 128;
    const int col0 = blockIdx.y * 128;

    floatx4 acc[4][4] = {};

    const int srow = t >> 3;          // staging base row 0..31 step (+32/iter)
    const int skc  = (t & 7) * 8;     // staging k offset

    for (int k0 = 0; k0 < K; k0 += 64) {
        #pragma unroll
        for (int i = 0; i < 4; ++i) {
            const int r = srow + i * 32;
            *(short8*)&As[r][skc] =
                *(const short8*)(A + (long)(row0 + r) * ldA + k0 + skc);
            *(short8*)&Bs[r][skc] =
                *(const short8*)(Bm + (long)(col0 + r) * ldB + k0 + skc);
        }
        __syncthreads();

        #pragma unroll
        for (int kb = 0; kb < 2; ++kb) {
            short8 af[4], bfr[4];
            #pragma unroll
            for (int i = 0; i < 4; ++i)
                af[i]  = *(const short8*)&As[wm + i * 16 + lrow][kb * 32 + quad * 8];
            #pragma unroll
            for (int j = 0; j < 4; ++j)
                bfr[j] = *(const short8*)&Bs[wn + j * 16 + lrow][kb * 32 + quad * 8];
            #pragma unroll
            for (int i = 0; i < 4; ++i)
                #pragma unroll
                for (int j = 0; j < 4; ++j)
                    acc[i][j] = __builtin_amdgcn_mfma_f32_16x16x32_bf16(
                        af[i], bfr[j], acc[i][j], 0, 0, 0);
        }
        __syncthreads();
    }

    // ---- epilogue. C/D layout: col=lane&15, row=(lane>>4)*4+reg
    float rs[4][4], rss[4][4];
    if (STATS) {
        #pragma unroll
        for (int i = 0; i < 4; ++i)
            #pragma unroll
            for (int rg = 0; rg < 4; ++rg) { rs[i][rg] = 0.f; rss[i][rg] = 0.f; }
    }
    #pragma unroll
    for (int j = 0; j < 4; ++j) {
        const int col = col0 + wn + j * 16 + lrow;
        const float bv = bias ? bias[col] : 0.0f;
        #pragma unroll
        for (int i = 0; i < 4; ++i) {
            const int rbase = row0 + wm + i * 16 + quad * 4;
            #pragma unroll
            for (int reg = 0; reg < 4; ++reg) {
                const float val = acc[i][j][reg] * scale + bv;
                const int r = rbase + reg;
                if (STATS) { rs[i][reg] += val; rss[i][reg] += val * val; }
                if (outMode == 0) {
                    ((float*)Cc)[(long)bz * sC + (long)r * ldC + col] = val;
                } else if (outMode == 1) {
                    ((unsigned short*)Cc)[(long)bz * sC + (long)r * ldC + col] = f2bu(val);
                } else {
                    ((unsigned short*)Cc)[((long)(r >> 9)) * 65536 + (long)col * 512 + (r & 511)] = f2bu(val);
                }
            }
        }
    }
    if (STATS) {
        // per-row partial over this wave's 64 cols: reduce over 16 lrow lanes
        #pragma unroll
        for (int i = 0; i < 4; ++i) {
            #pragma unroll
            for (int reg = 0; reg < 4; ++reg) {
                float s = rs[i][reg], ss = rss[i][reg];
                #pragma unroll
                for (int off = 1; off < 16; off <<= 1) {
                    s  += __shfl_xor(s,  off);
                    ss += __shfl_xor(ss, off);
                }
                if (lrow == 0) {
                    const int r = row0 + wm + i * 16 + quad * 4 + reg;
                    atomicAdd(&statsOut[r],      s);
                    atomicAdd(&statsOut[C_ + r], ss);
                }
            }
        }
    }
}

// ---------------------------------------------------------------------------
// Fused scores + softmax: per block, 64 full rows (all 512 cols) of one batch.
//   S = scale * q @ k^T  -> softmax rows in-register -> fp32 attn + bf16 copy.
// 4 waves; wave w owns cols [w*128, w*128+128). acc = 4x8 tiles of 16x16.
// BK=32 staging (qs 5KB + ks 41KB LDS) to keep 2 blocks/CU.
// ---------------------------------------------------------------------------
__global__ __launch_bounds__(256)
void scores_softmax_kernel(const unsigned short* __restrict__ q_bf,
                           const unsigned short* __restrict__ k_bf,
                           float* __restrict__ attn,
                           unsigned short* __restrict__ attnbf,
                           float scale)
{
    const int b  = blockIdx.y;
    const int r0 = blockIdx.x * 64;

    const unsigned short* qg = q_bf + (long)b * C_ * M_;
    const unsigned short* kg = k_bf + (long)b * C_ * M_;
    float* ab           = attn   + (long)b * C_ * C_;
    unsigned short* abf = attnbf + (long)b * C_ * C_;

    __shared__ unsigned short qs[64][40];
    __shared__ unsigned short ks[512][40];
    __shared__ float red[64][4];

    const int t    = threadIdx.x;
    const int lane = t & 63;
    const int wave = t >> 6;
    const int lrow = lane & 15;
    const int quad = lane >> 4;
    const int cb   = wave * 128;      // column base of this wave

    floatx4 acc[4][8] = {};

    const int sr = t >> 2;            // staging row 0..63
    const int sc = (t & 3) * 8;       // staging k offset (bf16 elems)

    for (int k0 = 0; k0 < M_; k0 += 32) {
        *(short8*)&qs[sr][sc] = *(const short8*)(qg + (long)(r0 + sr) * M_ + k0 + sc);
        #pragma unroll
        for (int i = 0; i < 8; ++i) {
            const int r = sr + i * 64;
            *(short8*)&ks[r][sc] = *(const short8*)(kg + (long)r * M_ + k0 + sc);
        }
        __syncthreads();

        short8 af[4];
        #pragma unroll
        for (int i = 0; i < 4; ++i)
            af[i] = *(const short8*)&qs[i * 16 + lrow][quad * 8];
        #pragma unroll
        for (int j = 0; j < 8; ++j) {
            const short8 bfr = *(const short8*)&ks[cb + j * 16 + lrow][quad * 8];
            #pragma unroll
            for (int i = 0; i < 4; ++i)
                acc[i][j] = __builtin_amdgcn_mfma_f32_16x16x32_bf16(
                    af[i], bfr, acc[i][j], 0, 0, 0);
        }
        __syncthreads();
    }

    // ---- raw row max (lane holds rows i*16+quad*4+reg, 8 col-tiles each)
    float mx[4][4];
    #pragma unroll
    for (int i = 0; i < 4; ++i) {
        #pragma unroll
        for (int rg = 0; rg < 4; ++rg) {
            float m = acc[i][0][rg];
            #pragma unroll
            for (int j = 1; j < 8; ++j) m = fmaxf(m, acc[i][j][rg]);
            #pragma unroll
            for (int off = 1; off < 16; off <<= 1) m = fmaxf(m, __shfl_xor(m, off));
            mx[i][rg] = m;
        }
    }
    if (lrow == 0) {
        #pragma unroll
        for (int i = 0; i < 4; ++i)
            #pragma unroll
            for (int rg = 0; rg < 4; ++rg)
                red[i * 16 + quad * 4 + rg][wave] = mx[i][rg];
    }
    __syncthreads();
    #pragma unroll
    for (int i = 0; i < 4; ++i) {
        #pragma unroll
        for (int rg = 0; rg < 4; ++rg) {
            const int row = i * 16 + quad * 4 + rg;
            mx[i][rg] = fmaxf(fmaxf(red[row][0], red[row][1]),
                              fmaxf(red[row][2], red[row][3]));
        }
    }
    __syncthreads();   // red about to be reused for sums

    // ---- exp (scale folded in) + row sum
    float sm[4][4];
    #pragma unroll
    for (int i = 0; i < 4; ++i) {
        #pragma unroll
        for (int rg = 0; rg < 4; ++rg) {
            float s = 0.f;
            #pragma unroll
            for (int j = 0; j < 8; ++j) {
                const float e = __expf((acc[i][j][rg] - mx[i][rg]) * scale);
                acc[i][j][rg] = e;
                s += e;
            }
            #pragma unroll
            for (int off = 1; off < 16; off <<= 1) s += __shfl_xor(s, off);
            sm[i][rg] = s;
        }
    }
    if (lrow == 0) {
        #pragma unroll
        for (int i = 0; i < 4; ++i)
            #pragma unroll
            for (int rg = 0; rg < 4; ++rg)
                red[i * 16 + quad * 4 + rg][wave] = sm[i][rg];
    }
    __syncthreads();
    #pragma unroll
    for (int i = 0; i < 4; ++i) {
        #pragma unroll
        for (int rg = 0; rg < 4; ++rg) {
            const int row = i * 16 + quad * 4 + rg;
            sm[i][rg] = 1.0f / (red[row][0] + red[row][1] + red[row][2] + red[row][3]);
        }
    }

    // ---- write fp32 attn (output) + bf16 copy
    #pragma unroll
    for (int j = 0; j < 8; ++j) {
        const int col = cb + j * 16 + lrow;
        #pragma unroll
        for (int i = 0; i < 4; ++i) {
            const int rowb = r0 + i * 16 + quad * 4;
            #pragma unroll
            for (int rg = 0; rg < 4; ++rg) {
                const float p = acc[i][j][rg] * sm[i][rg];
                ab [(long)(rowb + rg) * C_ + col] = p;
                abf[(long)(rowb + rg) * C_ + col] = f2bu(p);
            }
        }
    }
}

// ---------------------------------------------------------------------------
// BN + ReLU + residual; finalizes mean/istd from raw atomic sums inline.
// ---------------------------------------------------------------------------
__global__ __launch_bounds__(256)
void bn_apply_kernel(const float* __restrict__ outp, const float* __restrict__ value,
                     const float* __restrict__ stats, const float* __restrict__ gamma,
                     const float* __restrict__ beta, float* __restrict__ out)
{
    const long i4 = (long)blockIdx.x * 256 + threadIdx.x;
    const int  c  = (int)((i4 >> 5) & (C_ - 1));

    const float invn = 1.0f / (float)(B_ * S_);
    const float mean = stats[c] * invn;
    const float var  = stats[C_ + c] * invn - mean * mean;
    const float istd = rsqrtf(var + BN_EPS);
    const float g    = gamma[c] * istd;
    const float bc   = beta[c] - mean * g;

    const float4 x = ((const float4*)outp)[i4];
    const float4 r = ((const float4*)value)[i4];
    float4 y;
    y.x = fmaxf(fmaf(x.x, g, bc), 0.f) + r.x;
    y.y = fmaxf(fmaf(x.y, g, bc), 0.f) + r.y;
    y.z = fmaxf(fmaf(x.z, g, bc), 0.f) + r.z;
    y.w = fmaxf(fmaf(x.w, g, bc), 0.f) + r.w;
    ((float4*)out)[i4] = y;
}

// ---------------------------------------------------------------------------
extern "C" void kernel_launch(void* const* d_in, const int* in_sizes, int n_in,
                              void* d_out, int out_size, void* d_ws, size_t ws_size,
                              hipStream_t stream)
{
    const float* query = (const float*)d_in[0];
    const float* key   = (const float*)d_in[1];
    const float* value = (const float*)d_in[2];
    const float* Wq    = (const float*)d_in[3];
    const float* bq    = (const float*)d_in[4];
    const float* Wk    = (const float*)d_in[5];
    const float* bk    = (const float*)d_in[6];
    const float* Wv    = (const float*)d_in[7];
    const float* bv    = (const float*)d_in[8];
    const float* Wf    = (const float*)d_in[9];
    const float* bf    = (const float*)d_in[10];
    const float* gamma = (const float*)d_in[11];
    const float* beta  = (const float*)d_in[12];

    const long BC  = (long)B_ * C_;       // 65536
    const long BCM = BC * M_;             // 33,554,432
    const long BCS = BC * S_;             //  8,388,608
    const long BCC = BC * C_;             // 33,554,432

    // ---- workspace carve (bf16 = ushort). All offsets 16B-aligned.
    unsigned short* w      = (unsigned short*)d_ws;
    unsigned short* q_bf   = w;                     // [BC, M]   (q,k,v contiguous)
    unsigned short* k_bf   = q_bf + BCM;
    unsigned short* v2_bf  = k_bf + BCM;
    unsigned short* attnbf = v2_bf + BCM;           // [B, C, C]
    unsigned short* vwT    = attnbf + BCC;          // [B, S, C]
    unsigned short* qin    = vwT + (long)B_ * S_ * C_;   // [BC, S] (q,k,v contiguous)
    unsigned short* kin    = qin + BCS;
    unsigned short* vin    = kin + BCS;
    unsigned short* Wq_bf  = vin + BCS;             // [M, S] x3 then Wf [S, M], contiguous
    unsigned short* Wf_bf  = Wq_bf + 3L * M_ * S_;
    float* outp  = (float*)(Wf_bf + (long)S_ * M_); // [BC, S] fp32
    float* stats = outp + BCS;                      // [2*C] raw sums (atomics)
    // packed biases live at the head of attnbf (dead until scores kernel runs)
    float* bqkv = (float*)attnbf;                   // [3][512]

    float* out0 = (float*)d_out;          // [B, C, S]
    float* attn = out0 + BCS;             // [B, C, C]

    const float scale = 1.0f / sqrtf((float)M_);
    dim3 blk(256);

    // 0. fp32 -> bf16 conversions (2 fused launches) + bias pack / stats zero
    f2bf3_kernel<<<dim3(4096, 3), blk, 0, stream>>>(query, key, value, qin, BCS / 8);
    f2bf4_kernel<<<dim3(32, 4), blk, 0, stream>>>(Wq, Wk, Wv, Wf, Wq_bf,
                                                  (long)M_ * S_ / 8);
    pack_bias_zero_stats<<<dim3(10), blk, 0, stream>>>(bq, bk, bv, bqkv, stats);

    // 1. q/k/v projections in ONE batched launch (z selects input/weight/bias)
    gemm_bf16<false><<<dim3(512, 4, 3), blk, 0, stream>>>(
        qin, Wq_bf, bqkv, q_bf, (int)BC, M_, S_, S_, S_, M_,
        BCS, (long)M_ * S_, BCM, 512, 1.0f, 1, nullptr);

    // 2+3. fused scores + softmax: fp32 attn (output 1) + bf16 copy
    scores_softmax_kernel<<<dim3(C_ / 64, B_), blk, 0, stream>>>(
        q_bf, k_bf, attn, attnbf, scale);

    // 4. vw = v2 @ Wf^T + bf -> bf16, stored TRANSPOSED as vwT[b][s][c]
    //    (bias fold exact: softmax rows sum to 1)
    gemm_bf16<false><<<dim3(512, 1, 1), blk, 0, stream>>>(
        v2_bf, Wf_bf, bf, vwT, (int)BC, S_, M_, M_, M_, 0,
        0, 0, 0, 0, 1.0f, 2, nullptr);

    // 5. outp = attn @ vw (NT via vwT) + fused BN partial sums via atomics
    gemm_bf16<true><<<dim3(4, 1, 128), blk, 0, stream>>>(
        attnbf, vwT, nullptr, outp, C_, S_, C_, C_, C_, S_,
        (long)C_ * C_, (long)S_ * C_, (long)C_ * S_, 0, 1.0f, 0, stats);

    // 6. BN finalize + ReLU + residual -> out0
    bn_apply_kernel<<<dim3(BCS / 4 / 256), blk, 0, stream>>>(
        outp, value, stats, gamma, beta, out0);
}

// Round 2
// 523.822 us; speedup vs baseline: 1.2566x; 1.2566x over previous
//
#include <hip/hip_runtime.h>
#include <math.h>

#define B_  128
#define C_  512
#define S_  128
#define M_  512
#define BN_EPS 1e-5f

typedef __attribute__((ext_vector_type(8))) short   short8;
typedef __attribute__((ext_vector_type(4))) float   floatx4;
typedef __attribute__((ext_vector_type(4))) unsigned short ushort4v;
typedef __attribute__((ext_vector_type(8))) unsigned short ushort8v;

// fp32 -> bf16 bits, round-to-nearest-even (finite inputs)
__device__ __forceinline__ unsigned short f2bu(float f) {
    union { float f; unsigned int u; } c; c.f = f;
    unsigned int u = c.u;
    return (unsigned short)((u + 0x7fffu + ((u >> 16) & 1u)) >> 16);
}

// ---------------------------------------------------------------------------
// fp32 -> bf16, 8 elems/thread, 4 weight matrices (each M_*S_ elems).
// ---------------------------------------------------------------------------
__global__ __launch_bounds__(256)
void f2bf4_kernel(const float* __restrict__ a0, const float* __restrict__ a1,
                  const float* __restrict__ a2, const float* __restrict__ a3,
                  unsigned short* __restrict__ out, long n8)
{
    const float* in = (blockIdx.y == 0) ? a0 : (blockIdx.y == 1) ? a1
                    : (blockIdx.y == 2) ? a2 : a3;
    unsigned short* o = out + (long)blockIdx.y * (n8 * 8);
    const long i = (long)blockIdx.x * 256 + threadIdx.x;
    if (i >= n8) return;
    const float4* p = (const float4*)in + 2 * i;
    const float4 x = p[0], y = p[1];
    ushort4v u0, u1;
    u0.x = f2bu(x.x); u0.y = f2bu(x.y); u0.z = f2bu(x.z); u0.w = f2bu(x.w);
    u1.x = f2bu(y.x); u1.y = f2bu(y.y); u1.z = f2bu(y.z); u1.w = f2bu(y.w);
    ((ushort4v*)o)[2 * i]     = u0;
    ((ushort4v*)o)[2 * i + 1] = u1;
}

// ---------------------------------------------------------------------------
// Pack bq/bk/bv contiguous ([3][512]) and zero the BN stats accumulators.
// ---------------------------------------------------------------------------
__global__ __launch_bounds__(256)
void pack_bias_zero_stats(const float* __restrict__ bq, const float* __restrict__ bk,
                          const float* __restrict__ bv, float* __restrict__ bqkv,
                          float* __restrict__ stats)
{
    const int t = blockIdx.x * 256 + threadIdx.x;
    if (t < 512)            bqkv[t] = bq[t];
    else if (t < 1024)      bqkv[t] = bk[t - 512];
    else if (t < 1536)      bqkv[t] = bv[t - 1024];
    else if (t < 1536 + 2 * C_) stats[t - 1536] = 0.f;
}

// ---------------------------------------------------------------------------
// Fused q/k/v projection: fp32 input converted to bf16 during staging.
//   out[z][row][col] = bf16( sum_k in_z[row][k] * W_z[col][k] + b_z[col] )
// Block: 64-row strip x all 512 cols, 8 waves (wave w -> cols w*64..w*64+63),
// K=128 in 4 steps of BK=32. A read exactly once. Output LDS-bounced for
// full-128B-line ushort8 stores.
// ---------------------------------------------------------------------------
__global__ __launch_bounds__(512, 4)
void proj_kernel(const float* __restrict__ qf, const float* __restrict__ kf,
                 const float* __restrict__ vf, const unsigned short* __restrict__ Wbf,
                 const float* __restrict__ bqkv, unsigned short* __restrict__ outbf)
{
    const int z = blockIdx.y;
    const float* A = (z == 0 ? qf : z == 1 ? kf : vf) + (long)blockIdx.x * 64 * S_;
    const unsigned short* W = Wbf + (long)z * M_ * S_;
    const float* bias = bqkv + z * M_;
    unsigned short* O = outbf + (long)z * ((long)B_ * C_ * M_) + (long)blockIdx.x * 64 * M_;

    __shared__ unsigned short As[64][40];
    __shared__ unsigned short Bs[512][40];

    const int t    = threadIdx.x;
    const int lane = t & 63;
    const int wave = t >> 6;          // 0..7
    const int lrow = lane & 15;
    const int quad = lane >> 4;
    const int cb   = wave * 64;

    floatx4 acc[4][4] = {};

    const int ar = t >> 3;            // 0..63  (A staging row)
    const int ac = (t & 7) * 4;       // 0..28  (A staging k, fp32 elems)
    const int sr = t >> 2;            // 0..127 (B staging row)
    const int sc = (t & 3) * 8;       // B staging k (bf16 elems)

    for (int k0 = 0; k0 < S_; k0 += 32) {
        const float4 av = *(const float4*)(A + (long)ar * S_ + k0 + ac);
        ushort4v au;
        au.x = f2bu(av.x); au.y = f2bu(av.y); au.z = f2bu(av.z); au.w = f2bu(av.w);
        *(ushort4v*)&As[ar][ac] = au;
        #pragma unroll
        for (int i = 0; i < 4; ++i) {
            const int r = sr + i * 128;
            *(short8*)&Bs[r][sc] = *(const short8*)(W + (long)r * S_ + k0 + sc);
        }
        __syncthreads();

        short8 af[4];
        #pragma unroll
        for (int i = 0; i < 4; ++i)
            af[i] = *(const short8*)&As[i * 16 + lrow][quad * 8];
        #pragma unroll
        for (int j = 0; j < 4; ++j) {
            const short8 bfr = *(const short8*)&Bs[cb + j * 16 + lrow][quad * 8];
            #pragma unroll
            for (int i = 0; i < 4; ++i)
                acc[i][j] = __builtin_amdgcn_mfma_f32_16x16x32_bf16(
                    af[i], bfr, acc[i][j], 0, 0, 0);
        }
        __syncthreads();
    }

    // ---- epilogue: bias add, LDS-bounce each 16x64 tile, ushort8 stores.
    // Per-wave private scratch inside Bs (all waves past final barrier).
    unsigned short* scr = &Bs[wave * 64][0];    // 5120 B region, use 16x72
    const int rr = lane >> 3;                   // 0..7
    const int rc = (lane & 7) * 8;              // 0..56
    #pragma unroll
    for (int i = 0; i < 4; ++i) {
        #pragma unroll
        for (int j = 0; j < 4; ++j) {
            const float bv = bias[cb + j * 16 + lrow];
            #pragma unroll
            for (int rg = 0; rg < 4; ++rg)
                scr[(quad * 4 + rg) * 72 + j * 16 + lrow] = f2bu(acc[i][j][rg] + bv);
        }
        #pragma unroll
        for (int p = 0; p < 2; ++p) {
            const int row = p * 8 + rr;         // 0..15 within tile
            const ushort8v v = *(const ushort8v*)&scr[row * 72 + rc];
            *(ushort8v*)&O[(long)(i * 16 + row) * M_ + cb + rc] = v;
        }
    }
}

// ---------------------------------------------------------------------------
// bf16 MFMA GEMM, NT form: C[i,j] = scale * sum_k A[i,k]*Bm[j,k] (+ bias[j])
//   Batched over blockIdx.z with element strides sA/sB/sC/sBias.
//   outMode 0: fp32 C [ldC];  1: bf16 C [ldC];
//           2: bf16 scattered vwT: addr = (r>>9)*65536 + col*512 + (r&511)
//   STATS: accumulate per-row sum/sumsq of fp32 output into statsOut (atomics).
// Tile: BM=BN=128, BK=64. 256 thr = 4 waves (2x2), wave 64x64 via 4x4 of
// 16x16x32 MFMA. LDS rows padded to 72 bf16.
// ---------------------------------------------------------------------------
template<bool STATS>
__global__ __launch_bounds__(256)
void gemm_bf16(const unsigned short* __restrict__ A, const unsigned short* __restrict__ Bm,
               const float* __restrict__ bias, void* __restrict__ Cc,
               int M, int N, int K, int ldA, int ldB, int ldC,
               long sA, long sB, long sC, long sBias, float scale, int outMode,
               float* __restrict__ statsOut)
{
    const int bz = blockIdx.z;
    A  += (long)bz * sA;
    Bm += (long)bz * sB;
    if (bias) bias += (long)bz * sBias;

    __shared__ unsigned short As[128][72];
    __shared__ unsigned short Bs[128][72];

    const int t    = threadIdx.x;
    const int lane = t & 63;
    const int wave = t >> 6;
    const int wm   = (wave >> 1) * 64;
    const int wn   = (wave & 1) * 64;
    const int lrow = lane & 15;
    const int quad = lane >> 4;
    const int row0 = blockIdx.x * 128;
    const int col0 = blockIdx.y * 128;

    floatx4 acc[4][4] = {};

    const int srow = t >> 3;
    const int skc  = (t & 7) * 8;

    for (int k0 = 0; k0 < K; k0 += 64) {
        #pragma unroll
        for (int i = 0; i < 4; ++i) {
            const int r = srow + i * 32;
            *(short8*)&As[r][skc] =
                *(const short8*)(A + (long)(row0 + r) * ldA + k0 + skc);
            *(short8*)&Bs[r][skc] =
                *(const short8*)(Bm + (long)(col0 + r) * ldB + k0 + skc);
        }
        __syncthreads();

        #pragma unroll
        for (int kb = 0; kb < 2; ++kb) {
            short8 af[4], bfr[4];
            #pragma unroll
            for (int i = 0; i < 4; ++i)
                af[i]  = *(const short8*)&As[wm + i * 16 + lrow][kb * 32 + quad * 8];
            #pragma unroll
            for (int j = 0; j < 4; ++j)
                bfr[j] = *(const short8*)&Bs[wn + j * 16 + lrow][kb * 32 + quad * 8];
            #pragma unroll
            for (int i = 0; i < 4; ++i)
                #pragma unroll
                for (int j = 0; j < 4; ++j)
                    acc[i][j] = __builtin_amdgcn_mfma_f32_16x16x32_bf16(
                        af[i], bfr[j], acc[i][j], 0, 0, 0);
        }
        __syncthreads();
    }

    float rs[4][4], rss[4][4];
    if (STATS) {
        #pragma unroll
        for (int i = 0; i < 4; ++i)
            #pragma unroll
            for (int rg = 0; rg < 4; ++rg) { rs[i][rg] = 0.f; rss[i][rg] = 0.f; }
    }
    #pragma unroll
    for (int j = 0; j < 4; ++j) {
        const int col = col0 + wn + j * 16 + lrow;
        const float bv = bias ? bias[col] : 0.0f;
        #pragma unroll
        for (int i = 0; i < 4; ++i) {
            const int rbase = row0 + wm + i * 16 + quad * 4;
            #pragma unroll
            for (int reg = 0; reg < 4; ++reg) {
                const float val = acc[i][j][reg] * scale + bv;
                const int r = rbase + reg;
                if (STATS) { rs[i][reg] += val; rss[i][reg] += val * val; }
                if (outMode == 0) {
                    ((float*)Cc)[(long)bz * sC + (long)r * ldC + col] = val;
                } else if (outMode == 1) {
                    ((unsigned short*)Cc)[(long)bz * sC + (long)r * ldC + col] = f2bu(val);
                } else {
                    ((unsigned short*)Cc)[((long)(r >> 9)) * 65536 + (long)col * 512 + (r & 511)] = f2bu(val);
                }
            }
        }
    }
    if (STATS) {
        #pragma unroll
        for (int i = 0; i < 4; ++i) {
            #pragma unroll
            for (int reg = 0; reg < 4; ++reg) {
                float s = rs[i][reg], ss = rss[i][reg];
                #pragma unroll
                for (int off = 1; off < 16; off <<= 1) {
                    s  += __shfl_xor(s,  off);
                    ss += __shfl_xor(ss, off);
                }
                if (lrow == 0) {
                    const int r = row0 + wm + i * 16 + quad * 4 + reg;
                    atomicAdd(&statsOut[r],      s);
                    atomicAdd(&statsOut[C_ + r], ss);
                }
            }
        }
    }
}

// ---------------------------------------------------------------------------
// Fused scores + softmax. Block = 64 rows x all 512 cols of one batch.
// 8 waves (wave w -> cols w*64..). XCD-swizzled so all 8 strips of a batch
// share one XCD's L2 (K panel fetched ~once per batch). Epilogue LDS-bounces
// for full-line float4 (fp32 attn) + ushort4 (bf16) stores.
// ---------------------------------------------------------------------------
__global__ __launch_bounds__(512, 4)
void scores_softmax_kernel(const unsigned short* __restrict__ q_bf,
                           const unsigned short* __restrict__ k_bf,
                           float* __restrict__ attn,
                           unsigned short* __restrict__ attnbf,
                           float scale)
{
    // bijective XCD swizzle: 1024 blocks, xcd = bid&7 (round-robin heuristic)
    const int bid = blockIdx.x;
    const int b   = (bid & 7) * 16 + ((bid >> 3) >> 3);   // batch 0..127
    const int r0  = ((bid >> 3) & 7) * 64;                // row strip

    const unsigned short* qg = q_bf + (long)b * C_ * M_;
    const unsigned short* kg = k_bf + (long)b * C_ * M_;
    float* ab           = attn   + (long)b * C_ * C_;
    unsigned short* abf = attnbf + (long)b * C_ * C_;

    __shared__ unsigned short qs[64][40];
    __shared__ unsigned short ks[512][40];
    __shared__ float red[64][9];

    const int t    = threadIdx.x;
    const int lane = t & 63;
    const int wave = t >> 6;          // 0..7
    const int lrow = lane & 15;
    const int quad = lane >> 4;
    const int cb   = wave * 64;

    floatx4 acc[4][4] = {};

    const int sr = t >> 2;            // 0..127
    const int sc = (t & 3) * 8;

    for (int k0 = 0; k0 < M_; k0 += 32) {
        if (t < 256)
            *(short8*)&qs[t >> 2][sc] =
                *(const short8*)(qg + (long)(r0 + (t >> 2)) * M_ + k0 + sc);
        #pragma unroll
        for (int i = 0; i < 4; ++i) {
            const int r = sr + i * 128;
            *(short8*)&ks[r][sc] = *(const short8*)(kg + (long)r * M_ + k0 + sc);
        }
        __syncthreads();

        short8 af[4];
        #pragma unroll
        for (int i = 0; i < 4; ++i)
            af[i] = *(const short8*)&qs[i * 16 + lrow][quad * 8];
        #pragma unroll
        for (int j = 0; j < 4; ++j) {
            const short8 bfr = *(const short8*)&ks[cb + j * 16 + lrow][quad * 8];
            #pragma unroll
            for (int i = 0; i < 4; ++i)
                acc[i][j] = __builtin_amdgcn_mfma_f32_16x16x32_bf16(
                    af[i], bfr, acc[i][j], 0, 0, 0);
        }
        __syncthreads();
    }

    // ---- row max: per-lane over 4 col-tiles, 16-lane shfl, cross-wave via red
    float mx[4][4];
    #pragma unroll
    for (int i = 0; i < 4; ++i) {
        #pragma unroll
        for (int rg = 0; rg < 4; ++rg) {
            float m = fmaxf(fmaxf(acc[i][0][rg], acc[i][1][rg]),
                            fmaxf(acc[i][2][rg], acc[i][3][rg]));
            #pragma unroll
            for (int off = 1; off < 16; off <<= 1) m = fmaxf(m, __shfl_xor(m, off));
            mx[i][rg] = m;
        }
    }
    if (lrow == 0) {
        #pragma unroll
        for (int i = 0; i < 4; ++i)
            #pragma unroll
            for (int rg = 0; rg < 4; ++rg)
                red[i * 16 + quad * 4 + rg][wave] = mx[i][rg];
    }
    __syncthreads();
    #pragma unroll
    for (int i = 0; i < 4; ++i) {
        #pragma unroll
        for (int rg = 0; rg < 4; ++rg) {
            const int row = i * 16 + quad * 4 + rg;
            float m = red[row][0];
            #pragma unroll
            for (int w = 1; w < 8; ++w) m = fmaxf(m, red[row][w]);
            mx[i][rg] = m;
        }
    }
    __syncthreads();   // red reused for sums

    // ---- exp (scale folded) + row sum
    float sm[4][4];
    #pragma unroll
    for (int i = 0; i < 4; ++i) {
        #pragma unroll
        for (int rg = 0; rg < 4; ++rg) {
            float s = 0.f;
            #pragma unroll
            for (int j = 0; j < 4; ++j) {
                const float e = __expf((acc[i][j][rg] - mx[i][rg]) * scale);
                acc[i][j][rg] = e;
                s += e;
            }
            #pragma unroll
            for (int off = 1; off < 16; off <<= 1) s += __shfl_xor(s, off);
            sm[i][rg] = s;
        }
    }
    if (lrow == 0) {
        #pragma unroll
        for (int i = 0; i < 4; ++i)
            #pragma unroll
            for (int rg = 0; rg < 4; ++rg)
                red[i * 16 + quad * 4 + rg][wave] = sm[i][rg];
    }
    __syncthreads();
    #pragma unroll
    for (int i = 0; i < 4; ++i) {
        #pragma unroll
        for (int rg = 0; rg < 4; ++rg) {
            const int row = i * 16 + quad * 4 + rg;
            float s = red[row][0];
            #pragma unroll
            for (int w = 1; w < 8; ++w) s += red[row][w];
            sm[i][rg] = 1.0f / s;
        }
    }
    __syncthreads();   // all waves done with red/ks reads -> scratch reuse safe

    // ---- write phase: LDS-bounce each 16x64 fp32 tile for full-line stores.
    float* scr = (float*)&ks[wave * 64][0];   // 5120 B per-wave region, 16x68
    const int rr = lane >> 3;                 // 0..7
    const int rc = (lane & 7) * 4;            // 0..28
    #pragma unroll
    for (int i = 0; i < 4; ++i) {
        #pragma unroll
        for (int j = 0; j < 4; ++j)
            #pragma unroll
            for (int rg = 0; rg < 4; ++rg)
                scr[(quad * 4 + rg) * 68 + j * 16 + lrow] = acc[i][j][rg] * sm[i][rg];
        #pragma unroll
        for (int pr = 0; pr < 2; ++pr) {
            #pragma unroll
            for (int pc = 0; pc < 2; ++pc) {
                const int row = pr * 8 + rr;              // 0..15 in tile
                const int col = pc * 32 + rc;             // 0..60 in tile
                const float4 v = *(const float4*)&scr[row * 68 + col];
                const long gr = r0 + i * 16 + row;
                const long gc = cb + col;
                *(float4*)&ab[gr * C_ + gc] = v;
                ushort4v u;
                u.x = f2bu(v.x); u.y = f2bu(v.y); u.z = f2bu(v.z); u.w = f2bu(v.w);
                *(ushort4v*)&abf[gr * C_ + gc] = u;
            }
        }
    }
}

// ---------------------------------------------------------------------------
// BN + ReLU + residual; finalizes mean/istd from raw atomic sums inline.
// ---------------------------------------------------------------------------
__global__ __launch_bounds__(256)
void bn_apply_kernel(const float* __restrict__ outp, const float* __restrict__ value,
                     const float* __restrict__ stats, const float* __restrict__ gamma,
                     const float* __restrict__ beta, float* __restrict__ out)
{
    const long i4 = (long)blockIdx.x * 256 + threadIdx.x;
    const int  c  = (int)((i4 >> 5) & (C_ - 1));

    const float invn = 1.0f / (float)(B_ * S_);
    const float mean = stats[c] * invn;
    const float var  = stats[C_ + c] * invn - mean * mean;
    const float istd = rsqrtf(var + BN_EPS);
    const float g    = gamma[c] * istd;
    const float bc   = beta[c] - mean * g;

    const float4 x = ((const float4*)outp)[i4];
    const float4 r = ((const float4*)value)[i4];
    float4 y;
    y.x = fmaxf(fmaf(x.x, g, bc), 0.f) + r.x;
    y.y = fmaxf(fmaf(x.y, g, bc), 0.f) + r.y;
    y.z = fmaxf(fmaf(x.z, g, bc), 0.f) + r.z;
    y.w = fmaxf(fmaf(x.w, g, bc), 0.f) + r.w;
    ((float4*)out)[i4] = y;
}

// ---------------------------------------------------------------------------
extern "C" void kernel_launch(void* const* d_in, const int* in_sizes, int n_in,
                              void* d_out, int out_size, void* d_ws, size_t ws_size,
                              hipStream_t stream)
{
    const float* query = (const float*)d_in[0];
    const float* key   = (const float*)d_in[1];
    const float* value = (const float*)d_in[2];
    const float* Wq    = (const float*)d_in[3];
    const float* bq    = (const float*)d_in[4];
    const float* Wk    = (const float*)d_in[5];
    const float* bk    = (const float*)d_in[6];
    const float* Wv    = (const float*)d_in[7];
    const float* bv    = (const float*)d_in[8];
    const float* Wf    = (const float*)d_in[9];
    const float* bf    = (const float*)d_in[10];
    const float* gamma = (const float*)d_in[11];
    const float* beta  = (const float*)d_in[12];

    const long BC  = (long)B_ * C_;       // 65536
    const long BCM = BC * M_;             // 33,554,432
    const long BCS = BC * S_;             //  8,388,608
    const long BCC = BC * C_;             // 33,554,432

    // ---- workspace carve (bf16 = ushort). All offsets 16B-aligned.
    unsigned short* w      = (unsigned short*)d_ws;
    unsigned short* q_bf   = w;                     // [BC, M] (q,k,v contiguous)
    unsigned short* k_bf   = q_bf + BCM;
    unsigned short* v2_bf  = k_bf + BCM;
    unsigned short* attnbf = v2_bf + BCM;           // [B, C, C]
    unsigned short* vwT    = attnbf + BCC;          // [B, S, C]
    unsigned short* Wq_bf  = vwT + (long)B_ * S_ * C_;  // [M,S]x3 then Wf [S,M]
    unsigned short* Wf_bf  = Wq_bf + 3L * M_ * S_;
    float* outp  = (float*)(Wf_bf + (long)S_ * M_); // [BC, S] fp32
    float* stats = outp + BCS;                      // [2*C] raw sums (atomics)
    // packed biases at head of attnbf (dead until scores kernel runs)
    float* bqkv = (float*)attnbf;                   // [3][512]

    float* out0 = (float*)d_out;          // [B, C, S]
    float* attn = out0 + BCS;             // [B, C, C]

    const float scale = 1.0f / sqrtf((float)M_);
    dim3 blk(256);
    dim3 blk512(512);

    // 0. weight conversions + bias pack / stats zero
    f2bf4_kernel<<<dim3(32, 4), blk, 0, stream>>>(Wq, Wk, Wv, Wf, Wq_bf,
                                                  (long)M_ * S_ / 8);
    pack_bias_zero_stats<<<dim3(10), blk, 0, stream>>>(bq, bk, bv, bqkv, stats);

    // 1. q/k/v projections (fused fp32->bf16 staging, A read once)
    proj_kernel<<<dim3(1024, 3), blk512, 0, stream>>>(
        query, key, value, Wq_bf, bqkv, q_bf);

    // 2+3. fused scores + softmax: fp32 attn (output 2) + bf16 copy
    scores_softmax_kernel<<<dim3(1024), blk512, 0, stream>>>(
        q_bf, k_bf, attn, attnbf, scale);

    // 4. vw = v2 @ Wf^T + bf -> bf16, stored TRANSPOSED as vwT[b][s][c]
    //    (bias fold exact: softmax rows sum to 1)
    gemm_bf16<false><<<dim3(512, 1, 1), blk, 0, stream>>>(
        v2_bf, Wf_bf, bf, vwT, (int)BC, S_, M_, M_, M_, 0,
        0, 0, 0, 0, 1.0f, 2, nullptr);

    // 5. outp = attn @ vw (NT via vwT) + fused BN partial sums via atomics
    gemm_bf16<true><<<dim3(4, 1, 128), blk, 0, stream>>>(
        attnbf, vwT, nullptr, outp, C_, S_, C_, C_, C_, S_,
        (long)C_ * C_, (long)S_ * C_, (long)C_ * S_, 0, 1.0f, 0, stats);

    // 6. BN finalize + ReLU + residual -> out0
    bn_apply_kernel<<<dim3(BCS / 4 / 256), blk, 0, stream>>>(
        outp, value, stats, gamma, beta, out0);
}